// Round 2
// baseline (157.409 us; speedup 1.0000x reference)
//
#include <hip/hip_runtime.h>
#include <hip/hip_bf16.h>
#include <math.h>

using f32x4 = __attribute__((ext_vector_type(4))) float;
using s16x8 = __attribute__((ext_vector_type(8))) short;
using s16x4 = __attribute__((ext_vector_type(4))) short;

__device__ __forceinline__ unsigned short f2bf(float f) {
  unsigned int u = __builtin_bit_cast(unsigned int, f);
  u += 0x7FFFu + ((u >> 16) & 1u);
  return (unsigned short)(u >> 16);
}
__device__ __forceinline__ float bf2f(unsigned short h) {
  unsigned int u = ((unsigned int)h) << 16;
  return __builtin_bit_cast(float, u);
}
__device__ __forceinline__ float lrelu(float v) { return v > 0.f ? v : 0.01f * v; }

// ---------------------------------------------------------------------------
// Kernel 1: x1t[n][c], x2t[n][c], x3[c][n]  (bf16) = lrelu(Wi @ x + bi)
// grid 1024 (b*256 + nchunk16), block 256. 4 blocks/CU -> 16 waves/CU.
// ---------------------------------------------------------------------------
__global__ __launch_bounds__(256) void k1_conv3(
    const float* __restrict__ x,
    const float* __restrict__ W1, const float* __restrict__ b1,
    const float* __restrict__ W2, const float* __restrict__ b2,
    const float* __restrict__ W3, const float* __restrict__ b3,
    unsigned short* __restrict__ x1t, unsigned short* __restrict__ x2t,
    unsigned short* __restrict__ x3) {
  __shared__ float Wt[3][64][65];           // Wt[w][k][c] = W[c][k]
  __shared__ alignas(16) float sX[64][20];  // sX[k][n'] (reads are broadcast)
  __shared__ float sB[64][17];              // x3 transpose bounce (17: odd stride)
  const int t = threadIdx.x;
  const int b = blockIdx.x >> 8;
  const int n0 = (blockIdx.x & 255) << 4;

  const float* Ws[3] = {W1, W2, W3};
  for (int e = t; e < 12288; e += 256) {
    const int w = e >> 12, idx = e & 4095;
    Wt[w][idx & 63][idx >> 6] = Ws[w][idx];
  }
  {
    const int k = t >> 2, q = t & 3;
    *(float4*)&sX[k][q * 4] = *(const float4*)(x + ((size_t)b * 64 + k) * 4096 + n0 + q * 4);
  }
  __syncthreads();

  const int c = t & 63, g = t >> 6; // this thread: channel c, n' = g*4+j
  float y1[4], y2[4], y3[4];
  const float bb1 = b1[c], bb2 = b2[c], bb3 = b3[c];
#pragma unroll
  for (int j = 0; j < 4; ++j) { y1[j] = bb1; y2[j] = bb2; y3[j] = bb3; }

  for (int k = 0; k < 64; ++k) {
    const float w1 = Wt[0][k][c], w2 = Wt[1][k][c], w3 = Wt[2][k][c];
#pragma unroll
    for (int j = 0; j < 4; ++j) {
      const float xs = sX[k][g * 4 + j];
      y1[j] = __builtin_fmaf(w1, xs, y1[j]);
      y2[j] = __builtin_fmaf(w2, xs, y2[j]);
      y3[j] = __builtin_fmaf(w3, xs, y3[j]);
    }
  }
#pragma unroll
  for (int j = 0; j < 4; ++j) {
    const size_t n = (size_t)n0 + g * 4 + j;
    x1t[((size_t)b * 4096 + n) * 64 + c] = f2bf(lrelu(y1[j]));
    x2t[((size_t)b * 4096 + n) * 64 + c] = f2bf(lrelu(y2[j]));
    sB[c][g * 4 + j] = lrelu(y3[j]);
  }
  __syncthreads();
  {
    const int c2 = t >> 2, q = t & 3;
    s16x4 v;
#pragma unroll
    for (int jj = 0; jj < 4; ++jj) v[jj] = (short)f2bf(sB[c2][q * 4 + jj]);
    *(s16x4*)(x3 + ((size_t)b * 64 + c2) * 4096 + n0 + q * 4) = v;
  }
}

// ---------------------------------------------------------------------------
// Kernel 2: fused flash attention, in-block n-split.
// grid 256 (b*64 + mtile64), block 1024 = 16 waves = 4 m-subtiles x 4 n-splits.
// Each wave: 16 m's, 1024 n's (16 tiles of 64), online softmax, MFMA 16x16x32.
// Partials (m,l,O) merged across the 4 n-splits in LDS.
// ---------------------------------------------------------------------------
__global__ __launch_bounds__(1024, 4) void k2_attn(
    const unsigned short* __restrict__ x1t,
    const unsigned short* __restrict__ x2t,
    const unsigned short* __restrict__ x3,
    unsigned short* __restrict__ attn) {
  __shared__ alignas(16) unsigned short Plds[16][1024]; // per-wave P^T (16m x 64n, swizzled)
  __shared__ float cO[16][16][65];                      // [wave][m][c] partial numerators
  __shared__ float sM[16][16];                          // [wave][m] running max
  __shared__ float sL[16][16];                          // [wave][m] running denom
  const int t = threadIdx.x;
  const int wave = t >> 6, lane = t & 63;
  const int l15 = lane & 15, lh = lane >> 4;
  const int b = blockIdx.x >> 6;
  const int m0 = (blockIdx.x & 63) << 6;
  const int msub = wave & 3, split = wave >> 2;
  const int mw = m0 + msub * 16;
  const int nb = split * 1024, ne = nb + 1024;

  const unsigned short* x1b = x1t + (size_t)b * 4096 * 64;
  const unsigned short* x2b = x2t + (size_t)b * 4096 * 64;
  const unsigned short* x3b = x3 + (size_t)b * 64 * 4096;

  // Q fragments (B-operand): lane holds x2t[mw+l15][lh*8 .. +7] (+32)
  s16x8 qf0, qf1;
  {
    const unsigned short* qp = x2b + ((size_t)(mw + l15)) * 64 + lh * 8;
    qf0 = *(const s16x8*)qp;
    qf1 = *(const s16x8*)(qp + 32);
  }

  f32x4 O[4];
#pragma unroll
  for (int s = 0; s < 4; ++s) O[s] = (f32x4){0.f, 0.f, 0.f, 0.f};
  float m_r = -INFINITY, l_r = 0.f;

  unsigned char* pb = (unsigned char*)&Plds[wave][0];
  const int swz = (l15 & 7) << 4;
  const int pw_byte = l15 * 128;

  const unsigned short* kbase = x1b + (size_t)l15 * 64 + lh * 8;
  const unsigned short* vbase = x3b + (size_t)l15 * 4096 + lh * 8;

  s16x8 kf[4][2], vf[4][2];

  for (int nt = nb; nt < ne; nt += 64) {
#pragma unroll
    for (int s = 0; s < 4; ++s) { // A-frag QK: x1t[nt+s*16+l15][lh*8 + kk*32 + i]
      const unsigned short* p = kbase + (size_t)(nt + s * 16) * 64;
      kf[s][0] = *(const s16x8*)p;
      kf[s][1] = *(const s16x8*)(p + 32);
    }
#pragma unroll
    for (int s = 0; s < 4; ++s) { // A-frag PV: x3[s*16+l15][nt + lh*8 + kk*32 + i]
      const unsigned short* p = vbase + (size_t)s * 16 * 4096 + nt;
      vf[s][0] = *(const s16x8*)p;
      vf[s][1] = *(const s16x8*)(p + 32);
    }
    // ---- S = K^T Q : D[n_local, m], n on (reg, lh), m on l15
    f32x4 S[4];
#pragma unroll
    for (int s = 0; s < 4; ++s) {
      f32x4 z = {0.f, 0.f, 0.f, 0.f};
      z = __builtin_amdgcn_mfma_f32_16x16x32_bf16(kf[s][0], qf0, z, 0, 0, 0);
      S[s] = __builtin_amdgcn_mfma_f32_16x16x32_bf16(kf[s][1], qf1, z, 0, 0, 0);
    }
    // ---- online softmax over n (in-lane 16 + xor16 + xor32)
    float tmax = -INFINITY;
#pragma unroll
    for (int s = 0; s < 4; ++s)
#pragma unroll
      for (int r = 0; r < 4; ++r) tmax = fmaxf(tmax, S[s][r]);
    tmax = fmaxf(tmax, __shfl_xor(tmax, 16));
    tmax = fmaxf(tmax, __shfl_xor(tmax, 32));
    const float nm = fmaxf(m_r, tmax);
    const float sc = __expf(m_r - nm); // 0 on first tile
    float tsum = 0.f;
#pragma unroll
    for (int s = 0; s < 4; ++s)
#pragma unroll
      for (int r = 0; r < 4; ++r) {
        S[s][r] = __expf(S[s][r] - nm);
        tsum += S[s][r];
      }
    tsum += __shfl_xor(tsum, 16);
    tsum += __shfl_xor(tsum, 32);
    l_r = l_r * sc + tsum;
    m_r = nm;
#pragma unroll
    for (int s = 0; s < 4; ++s) O[s] *= sc;
    // ---- P -> bf16 -> per-wave LDS (P^T[m][n], XOR-swizzled rows)
#pragma unroll
    for (int s = 0; s < 4; ++s) {
      s16x4 pk;
#pragma unroll
      for (int r = 0; r < 4; ++r) pk[r] = (short)f2bf(S[s][r]);
      const int noff2 = (s * 16 + lh * 4) * 2;
      *(s16x4*)(pb + pw_byte + (noff2 ^ swz)) = pk;
    }
    // ---- B-frags of PV: P^T[m=l15][n = kk*32 + lh*8 + i]
    s16x8 pf0 = *(const s16x8*)(pb + pw_byte + ((lh * 16) ^ swz));
    s16x8 pf1 = *(const s16x8*)(pb + pw_byte + ((64 + lh * 16) ^ swz));
#pragma unroll
    for (int s = 0; s < 4; ++s) {
      O[s] = __builtin_amdgcn_mfma_f32_16x16x32_bf16(vf[s][0], pf0, O[s], 0, 0, 0);
      O[s] = __builtin_amdgcn_mfma_f32_16x16x32_bf16(vf[s][1], pf1, O[s], 0, 0, 0);
    }
  }

  // ---- publish per-wave partials
  if (lh == 0) { sM[wave][l15] = m_r; sL[wave][l15] = l_r; }
#pragma unroll
  for (int s = 0; s < 4; ++s)
#pragma unroll
    for (int r = 0; r < 4; ++r)
      cO[wave][l15][s * 16 + lh * 4 + r] = O[s][r];
  __syncthreads();

  // ---- combine 4 n-splits: thread t -> m = t&63, c = (t>>6)*4 + j
  const int mloc = t & 63, msub2 = mloc >> 4, ml = mloc & 15;
  const int cq = t >> 6;
  float Mx = -INFINITY;
#pragma unroll
  for (int s2 = 0; s2 < 4; ++s2) Mx = fmaxf(Mx, sM[msub2 + 4 * s2][ml]);
  float den = 0.f;
  float num[4] = {0.f, 0.f, 0.f, 0.f};
#pragma unroll
  for (int s2 = 0; s2 < 4; ++s2) {
    const int wv = msub2 + 4 * s2;
    const float w = __expf(sM[wv][ml] - Mx);
    den += sL[wv][ml] * w;
#pragma unroll
    for (int j = 0; j < 4; ++j) num[j] += cO[wv][ml][cq * 4 + j] * w;
  }
  const float inv = 1.f / den;
#pragma unroll
  for (int j = 0; j < 4; ++j)
    attn[((size_t)b * 64 + cq * 4 + j) * 4096 + m0 + mloc] = f2bf(num[j] * inv);
}

// ---------------------------------------------------------------------------
// Kernel 3: out = lrelu(W4 @ attn + b4) + x   (fp32 out, [b][c][n])
// grid 1024 (b*256 + nchunk16), block 256.
// ---------------------------------------------------------------------------
__global__ __launch_bounds__(256) void k3_conv4(
    const unsigned short* __restrict__ attn,
    const float* __restrict__ x,
    const float* __restrict__ W4, const float* __restrict__ b4,
    float* __restrict__ out) {
  __shared__ alignas(16) float Wt[64][68];    // Wt[k][c] = W4[c][k]
  __shared__ unsigned short sA[64][20];       // sA[k][n'] (reads broadcast)
  const int t = threadIdx.x;
  const int b = blockIdx.x >> 8;
  const int n0 = (blockIdx.x & 255) << 4;
  for (int e = t; e < 4096; e += 256) Wt[e & 63][e >> 6] = W4[e];
  {
    const int k = t >> 2, q = t & 3;
    *(s16x4*)&sA[k][q * 4] = *(const s16x4*)(attn + ((size_t)b * 64 + k) * 4096 + n0 + q * 4);
  }
  __syncthreads();
  const int nl = t & 15, cq = t >> 4; // thread: 4 channels (cq*4+ci), 1 n (nl)
  float acc[4];
#pragma unroll
  for (int ci = 0; ci < 4; ++ci) acc[ci] = b4[cq * 4 + ci];
  for (int k = 0; k < 64; ++k) {
    const float a = bf2f(sA[k][nl]);
    const float4 wv = *(const float4*)&Wt[k][cq * 4];
#pragma unroll
    for (int ci = 0; ci < 4; ++ci)
      acc[ci] = __builtin_fmaf(((const float*)&wv)[ci], a, acc[ci]);
  }
#pragma unroll
  for (int ci = 0; ci < 4; ++ci) {
    const size_t idx = ((size_t)b * 64 + cq * 4 + ci) * 4096 + n0 + nl;
    out[idx] = lrelu(acc[ci]) + x[idx];
  }
}

extern "C" void kernel_launch(void* const* d_in, const int* in_sizes, int n_in,
                              void* d_out, int out_size, void* d_ws, size_t ws_size,
                              hipStream_t stream) {
  const float* x = (const float*)d_in[0];
  const float* W1 = (const float*)d_in[1];
  const float* b1 = (const float*)d_in[2];
  const float* W2 = (const float*)d_in[3];
  const float* b2 = (const float*)d_in[4];
  const float* W3 = (const float*)d_in[5];
  const float* b3 = (const float*)d_in[6];
  const float* W4 = (const float*)d_in[7];
  const float* b4 = (const float*)d_in[8];
  float* out = (float*)d_out;

  const size_t planes = (size_t)4 * 4096 * 64; // 1M bf16 elems each
  unsigned short* x1t = (unsigned short*)d_ws;
  unsigned short* x2t = x1t + planes;
  unsigned short* x3 = x2t + planes;
  unsigned short* attn = x3 + planes;

  hipLaunchKernelGGL(k1_conv3, dim3(1024), dim3(256), 0, stream,
                     x, W1, b1, W2, b2, W3, b3, x1t, x2t, x3);
  hipLaunchKernelGGL(k2_attn, dim3(256), dim3(1024), 0, stream, x1t, x2t, x3, attn);
  hipLaunchKernelGGL(k3_conv4, dim3(1024), dim3(256), 0, stream, attn, x, W4, b4, out);
}

// Round 3
// 72.186 us; speedup vs baseline: 2.1806x; 2.1806x over previous
//
#include <hip/hip_runtime.h>
#include <hip/hip_bf16.h>
#include <math.h>

using f32x4 = __attribute__((ext_vector_type(4))) float;
using s16x8 = __attribute__((ext_vector_type(8))) short;
using s16x4 = __attribute__((ext_vector_type(4))) short;

__device__ __forceinline__ unsigned short f2bf(float f) {
  unsigned int u = __builtin_bit_cast(unsigned int, f);
  u += 0x7FFFu + ((u >> 16) & 1u);
  return (unsigned short)(u >> 16);
}
__device__ __forceinline__ float bf2f(unsigned short h) {
  unsigned int u = ((unsigned int)h) << 16;
  return __builtin_bit_cast(float, u);
}
__device__ __forceinline__ float lrelu(float v) { return v > 0.f ? v : 0.01f * v; }

#define GLL16(src, dst)                                                        \
  __builtin_amdgcn_global_load_lds(                                            \
      (const __attribute__((address_space(1))) void*)(src),                    \
      (__attribute__((address_space(3))) void*)(dst), 16, 0, 0)

// ---------------------------------------------------------------------------
// Kernel 1: x1t[n][c], x2t[n][c], x3[c][n]  (bf16) = lrelu(Wi @ x + bi)
// grid 512 (b*128 + nchunk32), block 256.
// ---------------------------------------------------------------------------
__global__ __launch_bounds__(256) void k1_conv3(
    const float* __restrict__ x,
    const float* __restrict__ W1, const float* __restrict__ b1,
    const float* __restrict__ W2, const float* __restrict__ b2,
    const float* __restrict__ W3, const float* __restrict__ b3,
    unsigned short* __restrict__ x1t, unsigned short* __restrict__ x2t,
    unsigned short* __restrict__ x3) {
  __shared__ float Wt[3][64][65];          // Wt[w][k][c] = W[c][k]
  __shared__ alignas(16) float sX[64][36]; // sX[k][n']
  __shared__ float sB[64][33];             // x3 transpose bounce
  const int t = threadIdx.x;
  const int b = blockIdx.x >> 7;
  const int n0 = (blockIdx.x & 127) << 5;

  const float* Ws[3] = {W1, W2, W3};
  for (int e = t; e < 12288; e += 256) {
    const int w = e >> 12, idx = e & 4095;
    Wt[w][idx & 63][idx >> 6] = Ws[w][idx];
  }
#pragma unroll
  for (int r = 0; r < 2; ++r) {
    const int idx = t + r * 256;
    const int k = idx >> 3, q = idx & 7;
    *(float4*)&sX[k][q * 4] = *(const float4*)(x + ((size_t)b * 64 + k) * 4096 + n0 + q * 4);
  }
  __syncthreads();

  const int c = t & 63, g = t >> 6; // channel c, n' = g*8+j (g == wave id)
  float y1[8], y2[8], y3[8];
  const float bb1 = b1[c], bb2 = b2[c], bb3 = b3[c];
#pragma unroll
  for (int j = 0; j < 8; ++j) { y1[j] = bb1; y2[j] = bb2; y3[j] = bb3; }

  for (int k = 0; k < 64; ++k) {
    const float w1 = Wt[0][k][c], w2 = Wt[1][k][c], w3 = Wt[2][k][c];
#pragma unroll
    for (int j = 0; j < 8; ++j) {
      const float xs = sX[k][g * 8 + j];
      y1[j] = __builtin_fmaf(w1, xs, y1[j]);
      y2[j] = __builtin_fmaf(w2, xs, y2[j]);
      y3[j] = __builtin_fmaf(w3, xs, y3[j]);
    }
  }
#pragma unroll
  for (int j = 0; j < 8; ++j) {
    const size_t n = (size_t)n0 + g * 8 + j;
    x1t[((size_t)b * 4096 + n) * 64 + c] = f2bf(lrelu(y1[j]));
    x2t[((size_t)b * 4096 + n) * 64 + c] = f2bf(lrelu(y2[j]));
    sB[c][g * 8 + j] = lrelu(y3[j]);
  }
  __syncthreads();
  {
    const int c2 = t >> 2, q = t & 3;
    s16x8 v;
#pragma unroll
    for (int jj = 0; jj < 8; ++jj) v[jj] = (short)f2bf(sB[c2][q * 8 + jj]);
    *(s16x8*)(x3 + ((size_t)b * 64 + c2) * 4096 + n0 + q * 8) = v;
  }
}

// ---------------------------------------------------------------------------
// Kernel 2: fused flash attention, LDS-staged K/V (pre-swizzled global_load_lds).
// grid 256 (b*64 + mtile64), block 1024 = 16 waves = msub(2: 32m) x split(8: 512n).
// Per split: 16 steps of 32n. K single-buffered, V double-buffered.
// LDS: K 8x4KB | V 8x2x4KB | P 16x2KB  (union with cO[16][32][65] + sM/sL).
// ---------------------------------------------------------------------------
#define KOFF 0
#define VOFF 32768
#define POFF 98304
#define SMSZ 137216

__global__ __launch_bounds__(1024, 4) void k2_attn(
    const unsigned short* __restrict__ x1t,
    const unsigned short* __restrict__ x2t,
    const unsigned short* __restrict__ x3,
    unsigned short* __restrict__ attn) {
  __shared__ __align__(16) char SM[SMSZ];
  char* smB = (char*)SM;

  const int t = threadIdx.x;
  const int wave = t >> 6, lane = t & 63;
  const int l15 = lane & 15, lh = lane >> 4;
  const int msub = wave & 1, split = wave >> 1;
  const int b = blockIdx.x >> 6;
  const int m0 = (blockIdx.x & 63) << 6;
  const int nb = split * 512;

  const char* x1B = (const char*)(x1t + (size_t)b * 4096 * 64); // [n][c] rows 128B
  const char* x3B = (const char*)(x3 + (size_t)b * 64 * 4096);  // [c][n] rows 8192B
  const unsigned short* x2b = x2t + (size_t)b * 4096 * 64;

  // ---- staging lane-offset precompute (pre-swizzled source, linear dest)
  int kSrcOff[2], vSrcOff[2];
  char* kDst[2];
  char* vDstB[2]; // without p*4096
#pragma unroll
  for (int i = 0; i < 2; ++i) {
    const int o = msub * 2048 + i * 1024 + lane * 16;
    {
      const int n = o >> 7;
      const int cb = (o & 127) ^ ((n & 7) << 4);
      kSrcOff[i] = n * 128 + cb;
      kDst[i] = smB + KOFF + split * 4096 + msub * 2048 + i * 1024;
    }
    {
      const int ch = o >> 7;
      const int rem = (o & 127) ^ ((ch & 7) << 4);
      const int c1 = rem >> 6, nbyt = rem & 63;
      vSrcOff[i] = (ch * 2 + c1) * 8192 + nbyt;
      vDstB[i] = smB + VOFF + split * 8192 + msub * 2048 + i * 1024;
    }
  }

  // ---- Q fragments (B-operand), persistent: qf[q2][kk]
  s16x8 qf[2][2];
#pragma unroll
  for (int q2 = 0; q2 < 2; ++q2) {
    const unsigned short* qp = x2b + (size_t)(m0 + msub * 32 + q2 * 16 + l15) * 64 + lh * 8;
    qf[q2][0] = *(const s16x8*)qp;
    qf[q2][1] = *(const s16x8*)(qp + 32);
  }

  f32x4 O[2][4];
#pragma unroll
  for (int q2 = 0; q2 < 2; ++q2)
#pragma unroll
    for (int s = 0; s < 4; ++s) O[q2][s] = (f32x4){0.f, 0.f, 0.f, 0.f};
  float m_r[2] = {-INFINITY, -INFINITY}, l_r[2] = {0.f, 0.f};

  // read-side constant swizzles
  const int swzK = (l15 & 7) << 4;
  const int swzV = ((l15 >> 1) & 7) << 4;
  const int swzP = swzV;

  // ---- prologue: stage K(0), V(0)->buf0, V(1)->buf1
#pragma unroll
  for (int i = 0; i < 2; ++i) {
    GLL16(x1B + (size_t)(nb + 0) * 128 + kSrcOff[i], kDst[i]);
    GLL16(x3B + (size_t)(nb + 0) * 2 + vSrcOff[i], vDstB[i]);
    GLL16(x3B + (size_t)(nb + 32) * 2 + vSrcOff[i], vDstB[i] + 4096);
  }
  __syncthreads();

  for (int j = 0; j < 16; ++j) {
    const int p = j & 1;
    // ---- QK: kf from Klds, S[q2][s2]
    s16x8 kf[2][2];
#pragma unroll
    for (int s2 = 0; s2 < 2; ++s2) {
      const int row = s2 * 16 + l15;
      const char* kp = smB + KOFF + split * 4096 + row * 128;
      kf[s2][0] = *(const s16x8*)(kp + ((lh * 16) ^ swzK));
      kf[s2][1] = *(const s16x8*)(kp + ((lh * 16 + 64) ^ swzK));
    }
    f32x4 S[2][2];
#pragma unroll
    for (int q2 = 0; q2 < 2; ++q2)
#pragma unroll
      for (int s2 = 0; s2 < 2; ++s2) {
        f32x4 z = {0.f, 0.f, 0.f, 0.f};
        z = __builtin_amdgcn_mfma_f32_16x16x32_bf16(kf[s2][0], qf[q2][0], z, 0, 0, 0);
        S[q2][s2] = __builtin_amdgcn_mfma_f32_16x16x32_bf16(kf[s2][1], qf[q2][1], z, 0, 0, 0);
      }
    __syncthreads(); // K buffer free; prior V stage drained
    if (j < 15) {
#pragma unroll
      for (int i = 0; i < 2; ++i)
        GLL16(x1B + (size_t)(nb + (j + 1) * 32) * 128 + kSrcOff[i], kDst[i]);
    }
    // ---- online softmax per q2 (n on (s2, r, lh))
#pragma unroll
    for (int q2 = 0; q2 < 2; ++q2) {
      float tmax = -INFINITY;
#pragma unroll
      for (int s2 = 0; s2 < 2; ++s2)
#pragma unroll
        for (int r = 0; r < 4; ++r) tmax = fmaxf(tmax, S[q2][s2][r]);
      tmax = fmaxf(tmax, __shfl_xor(tmax, 16));
      tmax = fmaxf(tmax, __shfl_xor(tmax, 32));
      const float nm = fmaxf(m_r[q2], tmax);
      const float sc = __expf(m_r[q2] - nm);
      float tsum = 0.f;
#pragma unroll
      for (int s2 = 0; s2 < 2; ++s2)
#pragma unroll
        for (int r = 0; r < 4; ++r) {
          S[q2][s2][r] = __expf(S[q2][s2][r] - nm);
          tsum += S[q2][s2][r];
        }
      tsum += __shfl_xor(tsum, 16);
      tsum += __shfl_xor(tsum, 32);
      l_r[q2] = l_r[q2] * sc + tsum;
      m_r[q2] = nm;
#pragma unroll
      for (int s = 0; s < 4; ++s) O[q2][s] *= sc;
      // P write: row m = q2*16+l15, nbytes s2*32+lh*8
      const int mh = q2 * 8 + (l15 >> 1), mlo = l15 & 1;
      char* pp = smB + POFF + wave * 2048 + mh * 128;
#pragma unroll
      for (int s2 = 0; s2 < 2; ++s2) {
        s16x4 pk;
#pragma unroll
        for (int r = 0; r < 4; ++r) pk[r] = (short)f2bf(S[q2][s2][r]);
        *(s16x4*)(pp + ((mlo * 64 + s2 * 32 + lh * 8) ^ swzP)) = pk;
      }
    }
    // ---- PV: vf from Vlds[p], pf from Plds
    const char* vp = smB + VOFF + split * 8192 + p * 4096;
    s16x8 vf[4], pf[2];
#pragma unroll
    for (int s = 0; s < 4; ++s) {
      const int c = s * 16 + l15;
      vf[s] = *(const s16x8*)(vp + (c >> 1) * 128 + (((c & 1) * 64 + lh * 16) ^ swzV));
    }
#pragma unroll
    for (int q2 = 0; q2 < 2; ++q2) {
      const int mh = q2 * 8 + (l15 >> 1), mlo = l15 & 1;
      pf[q2] = *(const s16x8*)(smB + POFF + wave * 2048 + mh * 128 + ((mlo * 64 + lh * 16) ^ swzP));
    }
#pragma unroll
    for (int q2 = 0; q2 < 2; ++q2)
#pragma unroll
      for (int s = 0; s < 4; ++s)
        O[q2][s] = __builtin_amdgcn_mfma_f32_16x16x32_bf16(vf[s], pf[q2], O[q2][s], 0, 0, 0);
    __syncthreads(); // V[p] readers done; K(j+1) drained
    if (j < 14) {
#pragma unroll
      for (int i = 0; i < 2; ++i)
        GLL16(x3B + (size_t)(nb + (j + 2) * 32) * 2 + vSrcOff[i], vDstB[i] + p * 4096);
    }
  }

  // ---- epilogue: publish partials into union region (K/V/P all dead)
  float* cO = (float*)smB;                  // [16][32][65]
  float* sM = (float*)(smB + 133120);       // [16*32]
  float* sL = (float*)(smB + 135168);       // [16*32]
#pragma unroll
  for (int q2 = 0; q2 < 2; ++q2) {
    if (lh == 0) {
      sM[wave * 32 + q2 * 16 + l15] = m_r[q2];
      sL[wave * 32 + q2 * 16 + l15] = l_r[q2];
    }
#pragma unroll
    for (int s = 0; s < 4; ++s)
#pragma unroll
      for (int r = 0; r < 4; ++r)
        cO[wave * 2080 + (q2 * 16 + l15) * 65 + s * 16 + lh * 4 + r] = O[q2][s][r];
  }
  __syncthreads();

  // ---- merge 8 n-splits: thread -> m = t&63, c = (t>>6)*4 + j
  {
    const int mm = t & 63, cq = t >> 6;
    const int msub2 = mm >> 5, ml = mm & 31;
    float Mx = -INFINITY;
#pragma unroll
    for (int s2 = 0; s2 < 8; ++s2) Mx = fmaxf(Mx, sM[(s2 * 2 + msub2) * 32 + ml]);
    float den = 0.f;
    float num[4] = {0.f, 0.f, 0.f, 0.f};
#pragma unroll
    for (int s2 = 0; s2 < 8; ++s2) {
      const int w = s2 * 2 + msub2;
      const float e = __expf(sM[w * 32 + ml] - Mx);
      den += sL[w * 32 + ml] * e;
      const float* co = cO + w * 2080 + ml * 65 + cq * 4;
#pragma unroll
      for (int jj = 0; jj < 4; ++jj) num[jj] += co[jj] * e;
    }
    const float inv = 1.f / den;
#pragma unroll
    for (int jj = 0; jj < 4; ++jj)
      attn[((size_t)b * 64 + cq * 4 + jj) * 4096 + m0 + mm] = f2bf(num[jj] * inv);
  }
}

// ---------------------------------------------------------------------------
// Kernel 3: out = lrelu(W4 @ attn + b4) + x   (fp32 out, [b][c][n])
// grid 512 (b*128 + nchunk32), block 256.
// ---------------------------------------------------------------------------
__global__ __launch_bounds__(256) void k3_conv4(
    const unsigned short* __restrict__ attn,
    const float* __restrict__ x,
    const float* __restrict__ W4, const float* __restrict__ b4,
    float* __restrict__ out) {
  __shared__ alignas(16) float Wt[64][68];      // Wt[k][c] = W4[c][k]
  __shared__ alignas(16) unsigned short sA[64][36];
  const int t = threadIdx.x;
  const int b = blockIdx.x >> 7;
  const int n0 = (blockIdx.x & 127) << 5;
  for (int e = t; e < 4096; e += 256) Wt[e & 63][e >> 6] = W4[e];
  {
    const int k = t >> 2, q = t & 3;
    *(s16x8*)&sA[k][q * 8] = *(const s16x8*)(attn + ((size_t)b * 64 + k) * 4096 + n0 + q * 8);
  }
  __syncthreads();
  const int nl = t & 31, cd = t >> 5; // 8 channels (cd*8+ci), 1 n
  float acc[8];
#pragma unroll
  for (int ci = 0; ci < 8; ++ci) acc[ci] = b4[cd * 8 + ci];
  for (int k = 0; k < 64; ++k) {
    const float a = bf2f(sA[k][nl]);
    const float4 w0 = *(const float4*)&Wt[k][cd * 8];
    const float4 w1 = *(const float4*)&Wt[k][cd * 8 + 4];
#pragma unroll
    for (int ci = 0; ci < 4; ++ci) {
      acc[ci] = __builtin_fmaf(((const float*)&w0)[ci], a, acc[ci]);
      acc[ci + 4] = __builtin_fmaf(((const float*)&w1)[ci], a, acc[ci + 4]);
    }
  }
#pragma unroll
  for (int ci = 0; ci < 8; ++ci) {
    const size_t idx = ((size_t)b * 64 + cd * 8 + ci) * 4096 + n0 + nl;
    out[idx] = lrelu(acc[ci]) + x[idx];
  }
}

extern "C" void kernel_launch(void* const* d_in, const int* in_sizes, int n_in,
                              void* d_out, int out_size, void* d_ws, size_t ws_size,
                              hipStream_t stream) {
  const float* x = (const float*)d_in[0];
  const float* W1 = (const float*)d_in[1];
  const float* b1 = (const float*)d_in[2];
  const float* W2 = (const float*)d_in[3];
  const float* b2 = (const float*)d_in[4];
  const float* W3 = (const float*)d_in[5];
  const float* b3 = (const float*)d_in[6];
  const float* W4 = (const float*)d_in[7];
  const float* b4 = (const float*)d_in[8];
  float* out = (float*)d_out;

  const size_t planes = (size_t)4 * 4096 * 64; // 1M bf16 elems each
  unsigned short* x1t = (unsigned short*)d_ws;
  unsigned short* x2t = x1t + planes;
  unsigned short* x3 = x2t + planes;
  unsigned short* attn = x3 + planes;

  hipLaunchKernelGGL(k1_conv3, dim3(512), dim3(256), 0, stream,
                     x, W1, b1, W2, b2, W3, b3, x1t, x2t, x3);
  hipLaunchKernelGGL(k2_attn, dim3(256), dim3(1024), 0, stream, x1t, x2t, x3, attn);
  hipLaunchKernelGGL(k3_conv4, dim3(512), dim3(256), 0, stream, attn, x, W4, b4, out);
}